// Round 9
// baseline (205.523 us; speedup 1.0000x reference)
//
#include <hip/hip_runtime.h>

#define NV 50000
#define NVP 50176
#define BDIM 64
#define DIN 1024
#define KFAN 32
#define DOUT 256
#define KSTEPS (DIN / 32)
#define XPK_N (KSTEPS * 512)   // uint4 elements per xpk copy (256 KB)
#define OPC_CHUNK 128
#define OPC_NCH (NVP / OPC_CHUNK)  // 392

typedef short bf16x8 __attribute__((ext_vector_type(8)));
typedef float f32x4 __attribute__((ext_vector_type(4)));

__device__ __forceinline__ unsigned short bf16_rtn(float f) {
  unsigned u = __float_as_uint(f);
  return (unsigned short)((u + 0x7fffu + ((u >> 16) & 1u)) >> 16);
}
__device__ __forceinline__ float bf16_to_f(unsigned short v) {
  return __uint_as_float(((unsigned)v) << 16);
}
__device__ __forceinline__ void gload_lds16(const void* g, void* l) {
  __builtin_amdgcn_global_load_lds(
      (const __attribute__((address_space(1))) void*)g,
      (__attribute__((address_space(3))) void*)l, 16, 0, 0);
}

// Pack x[64][1024] into MFMA B-fragment lane order (hi/lo bf16 split),
// replicated 8x so each XCD's L2 can hold a private copy.
__global__ __launch_bounds__(256) void pack_x(const float* __restrict__ x,
                                              uint4* __restrict__ xpk8) {
  int tid = blockIdx.x * 256 + threadIdx.x;  // 0..8191
  int ks = tid >> 8;
  int g = (tid >> 6) & 3;
  int l = tid & 63;
  int b = g * 16 + (l & 15);
  int k0 = ks * 32 + (l >> 4) * 8;
  unsigned hi[8], lo[8];
#pragma unroll
  for (int j = 0; j < 8; ++j) {
    float f = x[b * DIN + k0 + j];
    unsigned u = __float_as_uint(f);
    hi[j] = u >> 16;  // truncate to bf16
    float fh = __uint_as_float(u & 0xffff0000u);
    lo[j] = bf16_rtn(f - fh);
  }
  uint4 vh, vl;
  vh.x = hi[0] | (hi[1] << 16); vh.y = hi[2] | (hi[3] << 16);
  vh.z = hi[4] | (hi[5] << 16); vh.w = hi[6] | (hi[7] << 16);
  vl.x = lo[0] | (lo[1] << 16); vl.y = lo[2] | (lo[3] << 16);
  vl.z = lo[4] | (lo[5] << 16); vl.w = lo[6] | (lo[7] << 16);
  int idx = (ks * 4 + g) * 128 + l;
#pragma unroll
  for (int c = 0; c < 8; ++c) {
    xpk8[(size_t)c * XPK_N + idx] = vh;
    xpk8[(size_t)c * XPK_N + idx + 64] = vl;
  }
}

// h[n][b] = relu(sum_d W0[n][d]*x[b][d] + b0[n]) via split-bf16 MFMA.
// 3-deep circular LDS pipeline with counted vmcnt (T4): stage ks+2 at top
// of iter ks; before the barrier wait vmcnt(4) only (newest stage stays in
// flight). Never drain to 0 in the main loop.
__global__ __launch_bounds__(256) void layer0_mfma(
    const float* __restrict__ W0, const float* __restrict__ b0,
    const uint4* __restrict__ xpk8, unsigned short* __restrict__ h)
{
  __shared__ float wlds[3][64 * 32];  // 8 KB per buf, XOR-swizzled rows
  __shared__ uint4 xlds[3][512];      // 8 KB per buf, linear
  const int t = threadIdx.x;
  const int lane = t & 63;
  const int w = t >> 6;       // wave id: rows w*16..w*16+15
  const int rq = lane >> 4;
  const int rr = lane & 15;
  const int n0 = blockIdx.x * 64;
  const uint4* xsrc = xpk8 + (size_t)(blockIdx.x & 7) * XPK_N;

  // W staging slots (linear LDS dest, inverse-swizzled global source)
  int s_row[2], s_srcg[2];
#pragma unroll
  for (int p = 0; p < 2; ++p) {
    int flat = p * 256 + t;
    s_row[p] = flat >> 3;
    s_srcg[p] = (flat & 7) ^ (s_row[p] & 7);
  }
  int rowg0 = n0 + s_row[0]; if (rowg0 > NV - 1) rowg0 = NV - 1;
  int rowg1 = n0 + s_row[1]; if (rowg1 > NV - 1) rowg1 = NV - 1;
  const float* sp0 = W0 + (size_t)rowg0 * DIN + s_srcg[0] * 4;
  const float* sp1 = W0 + (size_t)rowg1 * DIN + s_srcg[1] * 4;

  // per-lane swizzled W ds_read offsets (floats)
  const int myrow = w * 16 + rr;
  const int sw = (myrow & 7) << 4;
  const int off0 = (myrow * 128 + ((rq * 32) ^ sw)) >> 2;
  const int off1 = (myrow * 128 + ((rq * 32 + 16) ^ sw)) >> 2;

  // stage kstep ks into buffer buf: 4 gload_lds16 per thread (vmcnt +4/wave)
  auto stage = [&](int ks, int buf) {
    const int ko = ks * 32;
    gload_lds16(sp0 + ko, &wlds[buf][(0 * 256 + t) * 4]);
    gload_lds16(sp1 + ko, &wlds[buf][(1 * 256 + t) * 4]);
    const uint4* xs = xsrc + ks * 512;
    gload_lds16(xs + (0 * 256 + t), &xlds[buf][0 * 256 + t]);
    gload_lds16(xs + (1 * 256 + t), &xlds[buf][1 * 256 + t]);
  };

  f32x4 acc[4];
#pragma unroll
  for (int g = 0; g < 4; ++g) acc[g] = (f32x4){0.f, 0.f, 0.f, 0.f};

  // prologue: stages 0 and 1 in flight; wait only for stage 0
  stage(0, 0);
  stage(1, 1);
  asm volatile("s_waitcnt vmcnt(4)" ::: "memory");
  __builtin_amdgcn_sched_barrier(0);
  __builtin_amdgcn_s_barrier();

  int cur = 0;
  for (int ks = 0; ks < KSTEPS; ++ks) {
    if (ks + 2 < KSTEPS) {
      int nb = cur + 2; if (nb >= 3) nb -= 3;
      stage(ks + 2, nb);
      __builtin_amdgcn_sched_barrier(0);  // pin stage issue before compute
    }
    // x fragments from LDS (8x ds_read_b128, lane-linear = conflict-free)
    const uint4* xb = &xlds[cur][0];
    uint4 xc[4][2];
#pragma unroll
    for (int g = 0; g < 4; ++g) {
      xc[g][0] = xb[g * 128 + lane];
      xc[g][1] = xb[g * 128 + 64 + lane];
    }
    // W fragment from LDS (2x ds_read_b128, <=2-way via XOR swizzle)
    const float* wb = &wlds[cur][0];
    float4 wv0 = *(const float4*)(wb + off0);
    float4 wv1 = *(const float4*)(wb + off1);
    bf16x8 whi, wlo;
    {
      float wf[8] = {wv0.x, wv0.y, wv0.z, wv0.w, wv1.x, wv1.y, wv1.z, wv1.w};
#pragma unroll
      for (int e = 0; e < 8; ++e) {
        unsigned u = __float_as_uint(wf[e]);
        whi[e] = (short)(u >> 16);
        float l = wf[e] - __uint_as_float(u & 0xffff0000u);
        wlo[e] = (short)bf16_rtn(l);
      }
    }
#pragma unroll
    for (int g = 0; g < 4; ++g) {
      bf16x8 xh = __builtin_bit_cast(bf16x8, xc[g][0]);
      bf16x8 xl = __builtin_bit_cast(bf16x8, xc[g][1]);
      acc[g] = __builtin_amdgcn_mfma_f32_16x16x32_bf16(whi, xh, acc[g], 0, 0, 0);
      acc[g] = __builtin_amdgcn_mfma_f32_16x16x32_bf16(wlo, xh, acc[g], 0, 0, 0);
      acc[g] = __builtin_amdgcn_mfma_f32_16x16x32_bf16(whi, xl, acc[g], 0, 0, 0);
    }
    // wait for stage ks+1 only (stage ks+2's 4 loads stay outstanding)
    if (ks + 2 < KSTEPS) {
      asm volatile("s_waitcnt vmcnt(4)" ::: "memory");
      __builtin_amdgcn_sched_barrier(0);
      __builtin_amdgcn_s_barrier();
    } else if (ks + 1 < KSTEPS) {
      asm volatile("s_waitcnt vmcnt(0)" ::: "memory");
      __builtin_amdgcn_sched_barrier(0);
      __builtin_amdgcn_s_barrier();
    }
    cur = (cur == 2) ? 0 : cur + 1;
  }

  // C layout: col = rr (b sub), row = rq*4 + r (n sub); rows of wave w
#pragma unroll
  for (int r = 0; r < 4; ++r) {
    int n = n0 + w * 16 + rq * 4 + r;
    if (n < NV) {
      float bias = b0[n];
#pragma unroll
      for (int g = 0; g < 4; ++g) {
        float v = fmaxf(acc[g][r] + bias, 0.f);
        h[(size_t)n * BDIM + g * 16 + rr] = bf16_rtn(v);
      }
    }
  }
}

// h_new[n][b] = relu(sum_k wv[n][k] * h[src[n][k]][b]); one wave per n.
__global__ __launch_bounds__(256) void sparse_layer(
    const unsigned short* __restrict__ hin, const float* __restrict__ wv,
    const int* __restrict__ src, unsigned short* __restrict__ hout)
{
  const int lane = threadIdx.x & 63;
  int n = blockIdx.x * 4 + (threadIdx.x >> 6);
  n = __builtin_amdgcn_readfirstlane(n);
  const float* wrow = wv + (size_t)n * KFAN;
  const int* srow = src + (size_t)n * KFAN;
  float acc = 0.f;
#pragma unroll
  for (int k = 0; k < KFAN; ++k) {
    int s = srow[k];      // uniform scalar load
    float w = wrow[k];    // uniform scalar load
    acc = fmaf(w, bf16_to_f(hin[(size_t)s * BDIM + lane]), acc);
  }
  hout[(size_t)n * BDIM + lane] = bf16_rtn(fmaxf(acc, 0.f));
}

// hT[b][n] = h[n][b]; coalesced reads, 16B/lane stores; zero-fills n-pad.
__global__ __launch_bounds__(256) void transpose_h(
    const unsigned short* __restrict__ h, unsigned short* __restrict__ hT)
{
  const int lane = threadIdx.x & 63;              // b
  const int wv = threadIdx.x >> 6;                // wave in block
  const int n0 = (blockIdx.x * 4 + wv) * 8;       // 8 n per wave
  unsigned short v[8];
#pragma unroll
  for (int i = 0; i < 8; ++i) {
    int n = n0 + i;
    v[i] = (n < NV) ? h[(size_t)n * BDIM + lane] : (unsigned short)0;
  }
  uint4 o;
  o.x = v[0] | ((unsigned)v[1] << 16);
  o.y = v[2] | ((unsigned)v[3] << 16);
  o.z = v[4] | ((unsigned)v[5] << 16);
  o.w = v[6] | ((unsigned)v[7] << 16);
  *(uint4*)(hT + (size_t)lane * NVP + n0) = o;
}

// part[dtile][chunk][d_local][b] over 128-n chunks, split-bf16 MFMA.
__global__ __launch_bounds__(64) void out_partial_mfma(
    const unsigned short* __restrict__ hT, const float* __restrict__ Wout,
    float* __restrict__ part)
{
  const int lane = threadIdx.x;
  const int rq = lane >> 4;
  const int rr = lane & 15;
  const int dtile = blockIdx.x;   // 0..3
  const int chunk = blockIdx.y;   // 0..391

  f32x4 acc[4][4];
#pragma unroll
  for (int f = 0; f < 4; ++f)
#pragma unroll
    for (int g = 0; g < 4; ++g) acc[f][g] = (f32x4){0.f, 0.f, 0.f, 0.f};

#pragma unroll
  for (int ks = 0; ks < OPC_CHUNK / 32; ++ks) {
    const int n0 = chunk * OPC_CHUNK + ks * 32 + rq * 8;
    bf16x8 hb[4];
#pragma unroll
    for (int g = 0; g < 4; ++g)
      hb[g] = *(const bf16x8*)(hT + (size_t)(g * 16 + rr) * NVP + n0);
    int nb = n0 > (NV - 8) ? (NV - 8) : n0;  // pad region: hb==0 -> contributes 0
#pragma unroll
    for (int f = 0; f < 4; ++f) {
      const float* wp = Wout + (size_t)(dtile * 64 + f * 16 + rr) * NV + nb;
      float4 a0 = *(const float4*)(wp);
      float4 a1 = *(const float4*)(wp + 4);
      float wf[8] = {a0.x, a0.y, a0.z, a0.w, a1.x, a1.y, a1.z, a1.w};
      bf16x8 whi, wlo;
#pragma unroll
      for (int e = 0; e < 8; ++e) {
        unsigned u = __float_as_uint(wf[e]);
        whi[e] = (short)(u >> 16);
        float l = wf[e] - __uint_as_float(u & 0xffff0000u);
        wlo[e] = (short)bf16_rtn(l);
      }
#pragma unroll
      for (int g = 0; g < 4; ++g) {
        acc[f][g] = __builtin_amdgcn_mfma_f32_16x16x32_bf16(whi, hb[g], acc[f][g], 0, 0, 0);
        acc[f][g] = __builtin_amdgcn_mfma_f32_16x16x32_bf16(wlo, hb[g], acc[f][g], 0, 0, 0);
      }
    }
  }
  float* pbase = part + ((size_t)dtile * OPC_NCH + chunk) * 4096;
#pragma unroll
  for (int f = 0; f < 4; ++f)
#pragma unroll
    for (int g = 0; g < 4; ++g)
#pragma unroll
      for (int r = 0; r < 4; ++r)
        pbase[(f * 16 + rq * 4 + r) * 64 + g * 16 + rr] = acc[f][g][r];
}

__global__ __launch_bounds__(256) void out_reduce(
    const float* __restrict__ part, const float* __restrict__ bout,
    float* __restrict__ out)
{
  int tid = blockIdx.x * 256 + threadIdx.x;  // 16384 threads
  int b = tid & 63;
  int d = tid >> 6;
  int dtile = d >> 6;
  int dd = d & 63;
  float s = bout[d];
  for (int c = 0; c < OPC_NCH; ++c)
    s += part[((size_t)dtile * OPC_NCH + c) * 4096 + dd * 64 + b];
  out[(size_t)b * DOUT + d] = s;
}

extern "C" void kernel_launch(void* const* d_in, const int* in_sizes, int n_in,
                              void* d_out, int out_size, void* d_ws, size_t ws_size,
                              hipStream_t stream)
{
  const float* x    = (const float*)d_in[0];
  const float* W0   = (const float*)d_in[1];
  const float* b0   = (const float*)d_in[2];
  const float* Wv   = (const float*)d_in[3];
  const float* Wout = (const float*)d_in[4];
  const float* bout = (const float*)d_in[5];
  const int*   src  = (const int*)d_in[6];
  float* out = (float*)d_out;

  char* ws = (char*)d_ws;
  const size_t hbf = (size_t)NV * BDIM * 2;       // 6.4 MB
  const size_t hTb = (size_t)NVP * BDIM * 2;      // 6.42 MB
  const size_t xpkb = (size_t)8 * XPK_N * 16;     // 2 MB
  unsigned short* hb0 = (unsigned short*)ws;
  unsigned short* hb1 = (unsigned short*)(ws + hbf);
  unsigned short* hT  = (unsigned short*)(ws + 2 * hbf);
  uint4* xpk8 = (uint4*)(ws + 2 * hbf + hTb);
  float* part = (float*)(ws + 2 * hbf + hTb + xpkb);  // 25.7 MB

  pack_x<<<32, 256, 0, stream>>>(x, xpk8);
  layer0_mfma<<<(NV + 63) / 64, 256, 0, stream>>>(W0, b0, xpk8, hb0);

  const size_t lstride = (size_t)NV * KFAN;
  sparse_layer<<<NV / 4, 256, 0, stream>>>(hb0, Wv, src, hb1);
  sparse_layer<<<NV / 4, 256, 0, stream>>>(hb1, Wv + lstride, src + lstride, hb0);
  sparse_layer<<<NV / 4, 256, 0, stream>>>(hb0, Wv + 2 * lstride, src + 2 * lstride, hb1);

  transpose_h<<<NVP / 32, 256, 0, stream>>>(hb1, hT);
  out_partial_mfma<<<dim3(4, OPC_NCH), 64, 0, stream>>>(hT, Wout, part);
  out_reduce<<<(BDIM * DOUT) / 256, 256, 0, stream>>>(part, bout, out);
}

// Round 10
// 202.896 us; speedup vs baseline: 1.0129x; 1.0129x over previous
//
#include <hip/hip_runtime.h>

#define NV 50000
#define NVP 50176
#define BDIM 64
#define DIN 1024
#define KFAN 32
#define DOUT 256
#define KSTEPS (DIN / 32)
#define XPK_N (KSTEPS * 512)   // uint4 elements per xpk copy (256 KB)
#define OPC_CHUNK 128
#define OPC_NCH (NVP / OPC_CHUNK)  // 392

typedef short bf16x8 __attribute__((ext_vector_type(8)));
typedef float f32x4 __attribute__((ext_vector_type(4)));

__device__ __forceinline__ unsigned short bf16_rtn(float f) {
  unsigned u = __float_as_uint(f);
  return (unsigned short)((u + 0x7fffu + ((u >> 16) & 1u)) >> 16);
}
__device__ __forceinline__ float bf16_to_f(unsigned short v) {
  return __uint_as_float(((unsigned)v) << 16);
}
__device__ __forceinline__ void gload_lds16(const void* g, void* l) {
  __builtin_amdgcn_global_load_lds(
      (const __attribute__((address_space(1))) void*)g,
      (__attribute__((address_space(3))) void*)l, 16, 0, 0);
}

// Pack x[64][1024] into MFMA B-fragment lane order (hi/lo bf16 split),
// replicated 8x so each XCD's L2 can hold a private copy.
__global__ __launch_bounds__(256) void pack_x(const float* __restrict__ x,
                                              uint4* __restrict__ xpk8) {
  int tid = blockIdx.x * 256 + threadIdx.x;  // 0..8191
  int ks = tid >> 8;
  int g = (tid >> 6) & 3;
  int l = tid & 63;
  int b = g * 16 + (l & 15);
  int k0 = ks * 32 + (l >> 4) * 8;
  unsigned hi[8], lo[8];
#pragma unroll
  for (int j = 0; j < 8; ++j) {
    float f = x[b * DIN + k0 + j];
    unsigned u = __float_as_uint(f);
    hi[j] = u >> 16;  // truncate to bf16
    float fh = __uint_as_float(u & 0xffff0000u);
    lo[j] = bf16_rtn(f - fh);
  }
  uint4 vh, vl;
  vh.x = hi[0] | (hi[1] << 16); vh.y = hi[2] | (hi[3] << 16);
  vh.z = hi[4] | (hi[5] << 16); vh.w = hi[6] | (hi[7] << 16);
  vl.x = lo[0] | (lo[1] << 16); vl.y = lo[2] | (lo[3] << 16);
  vl.z = lo[4] | (lo[5] << 16); vl.w = lo[6] | (lo[7] << 16);
  int idx = (ks * 4 + g) * 128 + l;
#pragma unroll
  for (int c = 0; c < 8; ++c) {
    xpk8[(size_t)c * XPK_N + idx] = vh;
    xpk8[(size_t)c * XPK_N + idx + 64] = vl;
  }
}

// h[n][b] = relu(sum_d W0[n][d]*x[b][d] + b0[n]) via split-bf16 MFMA.
// DRAM-page-friendly W staging: 8 super-steps of 128 d; each stage reads
// 512 B CONTIGUOUS per W0 row (vs 128 B before -> 4x bytes/page-activate).
// W tile 64x128 f32 double-buffered in LDS (64 KB, 2 blocks/CU); x read
// directly from the XCD-local packed copy per inner k-step.
__global__ __launch_bounds__(256) void layer0_mfma(
    const float* __restrict__ W0, const float* __restrict__ b0,
    const uint4* __restrict__ xpk8, unsigned short* __restrict__ h)
{
  __shared__ float wlds[2][64 * 128];  // 32 KB per buffer
  const int t = threadIdx.x;
  const int lane = t & 63;
  const int w = t >> 6;       // wave id: rows w*16..w*16+15
  const int rq = lane >> 4;
  const int rr = lane & 15;
  const int n0 = blockIdx.x * 64;
  const uint4* xsrc = xpk8 + (size_t)(blockIdx.x & 7) * XPK_N;

  // staging map: slot f = p*256+t -> row = f>>5, unit = f&31 (16B units of
  // the 512B row-chunk). LDS dest linear at f*16B; global source unit
  // swizzled su = unit ^ (row&31) (rule #21: swizzle source, read swizzled).
  const float* sp[8];
#pragma unroll
  for (int p = 0; p < 8; ++p) {
    int f = p * 256 + t;
    int row = f >> 5;
    int su = (f & 31) ^ (row & 31);
    int rg = n0 + row; if (rg > NV - 1) rg = NV - 1;
    sp[p] = W0 + (size_t)rg * DIN + su * 4;
  }
  auto stage = [&](int ss, int buf) {
    const int co = ss * 128;  // float offset along the row
#pragma unroll
    for (int p = 0; p < 8; ++p)
      gload_lds16(sp[p] + co, &wlds[buf][(p * 256 + t) * 4]);
  };

  // per-lane swizzled W read base (floats)
  const int myrow = w * 16 + rr;
  const int rowbase = myrow * 128;
  const int swz = myrow & 31;

  f32x4 acc[4];
#pragma unroll
  for (int g = 0; g < 4; ++g) acc[g] = (f32x4){0.f, 0.f, 0.f, 0.f};

  // prologue: both buffers staged; wait for stage 0 only
  stage(0, 0);
  stage(1, 1);
  asm volatile("s_waitcnt vmcnt(8)" ::: "memory");
  __builtin_amdgcn_sched_barrier(0);
  __builtin_amdgcn_s_barrier();

  for (int ss = 0; ss < 8; ++ss) {
    const int cur = ss & 1;
#pragma unroll
    for (int kk = 0; kk < 4; ++kk) {
      const int xb = (ss * 4 + kk) * 512;
      uint4 xc[4][2];
#pragma unroll
      for (int g = 0; g < 4; ++g) {
        xc[g][0] = xsrc[xb + g * 128 + lane];
        xc[g][1] = xsrc[xb + g * 128 + 64 + lane];
      }
      const int u0 = kk * 8 + rq * 2;
      const float* wb = &wlds[cur][0];
      float4 wv0 = *(const float4*)(wb + rowbase + ((u0 ^ swz) << 2));
      float4 wv1 = *(const float4*)(wb + rowbase + (((u0 + 1) ^ swz) << 2));
      bf16x8 whi, wlo;
      {
        float wf[8] = {wv0.x, wv0.y, wv0.z, wv0.w, wv1.x, wv1.y, wv1.z, wv1.w};
#pragma unroll
        for (int e = 0; e < 8; ++e) {
          unsigned u = __float_as_uint(wf[e]);
          whi[e] = (short)(u >> 16);
          float l = wf[e] - __uint_as_float(u & 0xffff0000u);
          wlo[e] = (short)bf16_rtn(l);
        }
      }
#pragma unroll
      for (int g = 0; g < 4; ++g) {
        bf16x8 xh = __builtin_bit_cast(bf16x8, xc[g][0]);
        bf16x8 xl = __builtin_bit_cast(bf16x8, xc[g][1]);
        acc[g] = __builtin_amdgcn_mfma_f32_16x16x32_bf16(whi, xh, acc[g], 0, 0, 0);
        acc[g] = __builtin_amdgcn_mfma_f32_16x16x32_bf16(wlo, xh, acc[g], 0, 0, 0);
        acc[g] = __builtin_amdgcn_mfma_f32_16x16x32_bf16(whi, xl, acc[g], 0, 0, 0);
      }
    }
    // all waves done reading wlds[cur]; x-waits inside the kk-loop have
    // FIFO-drained stage(ss+1), so buf cur^1 is fully landed for iter ss+1.
    __syncthreads();
    if (ss + 2 < 8) stage(ss + 2, cur);
  }

  // C layout: col = rr (b sub), row = rq*4 + r (n sub); rows of wave w
#pragma unroll
  for (int r = 0; r < 4; ++r) {
    int n = n0 + w * 16 + rq * 4 + r;
    if (n < NV) {
      float bias = b0[n];
#pragma unroll
      for (int g = 0; g < 4; ++g) {
        float v = fmaxf(acc[g][r] + bias, 0.f);
        h[(size_t)n * BDIM + g * 16 + rr] = bf16_rtn(v);
      }
    }
  }
}

// h_new[n][b] = relu(sum_k wv[n][k] * h[src[n][k]][b]); one wave per n.
__global__ __launch_bounds__(256) void sparse_layer(
    const unsigned short* __restrict__ hin, const float* __restrict__ wv,
    const int* __restrict__ src, unsigned short* __restrict__ hout)
{
  const int lane = threadIdx.x & 63;
  int n = blockIdx.x * 4 + (threadIdx.x >> 6);
  n = __builtin_amdgcn_readfirstlane(n);
  const float* wrow = wv + (size_t)n * KFAN;
  const int* srow = src + (size_t)n * KFAN;
  float acc = 0.f;
#pragma unroll
  for (int k = 0; k < KFAN; ++k) {
    int s = srow[k];      // uniform scalar load
    float w = wrow[k];    // uniform scalar load
    acc = fmaf(w, bf16_to_f(hin[(size_t)s * BDIM + lane]), acc);
  }
  hout[(size_t)n * BDIM + lane] = bf16_rtn(fmaxf(acc, 0.f));
}

// hT[b][n] = h[n][b]; coalesced reads, 16B/lane stores; zero-fills n-pad.
__global__ __launch_bounds__(256) void transpose_h(
    const unsigned short* __restrict__ h, unsigned short* __restrict__ hT)
{
  const int lane = threadIdx.x & 63;              // b
  const int wv = threadIdx.x >> 6;                // wave in block
  const int n0 = (blockIdx.x * 4 + wv) * 8;       // 8 n per wave
  unsigned short v[8];
#pragma unroll
  for (int i = 0; i < 8; ++i) {
    int n = n0 + i;
    v[i] = (n < NV) ? h[(size_t)n * BDIM + lane] : (unsigned short)0;
  }
  uint4 o;
  o.x = v[0] | ((unsigned)v[1] << 16);
  o.y = v[2] | ((unsigned)v[3] << 16);
  o.z = v[4] | ((unsigned)v[5] << 16);
  o.w = v[6] | ((unsigned)v[7] << 16);
  *(uint4*)(hT + (size_t)lane * NVP + n0) = o;
}

// part[dtile][chunk][d_local][b] over 128-n chunks, split-bf16 MFMA.
__global__ __launch_bounds__(64) void out_partial_mfma(
    const unsigned short* __restrict__ hT, const float* __restrict__ Wout,
    float* __restrict__ part)
{
  const int lane = threadIdx.x;
  const int rq = lane >> 4;
  const int rr = lane & 15;
  const int dtile = blockIdx.x;   // 0..3
  const int chunk = blockIdx.y;   // 0..391

  f32x4 acc[4][4];
#pragma unroll
  for (int f = 0; f < 4; ++f)
#pragma unroll
    for (int g = 0; g < 4; ++g) acc[f][g] = (f32x4){0.f, 0.f, 0.f, 0.f};

#pragma unroll
  for (int ks = 0; ks < OPC_CHUNK / 32; ++ks) {
    const int n0 = chunk * OPC_CHUNK + ks * 32 + rq * 8;
    bf16x8 hb[4];
#pragma unroll
    for (int g = 0; g < 4; ++g)
      hb[g] = *(const bf16x8*)(hT + (size_t)(g * 16 + rr) * NVP + n0);
    int nb = n0 > (NV - 8) ? (NV - 8) : n0;  // pad region: hb==0 -> contributes 0
#pragma unroll
    for (int f = 0; f < 4; ++f) {
      const float* wp = Wout + (size_t)(dtile * 64 + f * 16 + rr) * NV + nb;
      float4 a0 = *(const float4*)(wp);
      float4 a1 = *(const float4*)(wp + 4);
      float wf[8] = {a0.x, a0.y, a0.z, a0.w, a1.x, a1.y, a1.z, a1.w};
      bf16x8 whi, wlo;
#pragma unroll
      for (int e = 0; e < 8; ++e) {
        unsigned u = __float_as_uint(wf[e]);
        whi[e] = (short)(u >> 16);
        float l = wf[e] - __uint_as_float(u & 0xffff0000u);
        wlo[e] = (short)bf16_rtn(l);
      }
#pragma unroll
      for (int g = 0; g < 4; ++g) {
        acc[f][g] = __builtin_amdgcn_mfma_f32_16x16x32_bf16(whi, hb[g], acc[f][g], 0, 0, 0);
        acc[f][g] = __builtin_amdgcn_mfma_f32_16x16x32_bf16(wlo, hb[g], acc[f][g], 0, 0, 0);
      }
    }
  }
  float* pbase = part + ((size_t)dtile * OPC_NCH + chunk) * 4096;
#pragma unroll
  for (int f = 0; f < 4; ++f)
#pragma unroll
    for (int g = 0; g < 4; ++g)
#pragma unroll
      for (int r = 0; r < 4; ++r)
        pbase[(f * 16 + rq * 4 + r) * 64 + g * 16 + rr] = acc[f][g][r];
}

__global__ __launch_bounds__(256) void out_reduce(
    const float* __restrict__ part, const float* __restrict__ bout,
    float* __restrict__ out)
{
  int tid = blockIdx.x * 256 + threadIdx.x;  // 16384 threads
  int b = tid & 63;
  int d = tid >> 6;
  int dtile = d >> 6;
  int dd = d & 63;
  float s = bout[d];
  for (int c = 0; c < OPC_NCH; ++c)
    s += part[((size_t)dtile * OPC_NCH + c) * 4096 + dd * 64 + b];
  out[(size_t)b * DOUT + d] = s;
}

extern "C" void kernel_launch(void* const* d_in, const int* in_sizes, int n_in,
                              void* d_out, int out_size, void* d_ws, size_t ws_size,
                              hipStream_t stream)
{
  const float* x    = (const float*)d_in[0];
  const float* W0   = (const float*)d_in[1];
  const float* b0   = (const float*)d_in[2];
  const float* Wv   = (const float*)d_in[3];
  const float* Wout = (const float*)d_in[4];
  const float* bout = (const float*)d_in[5];
  const int*   src  = (const int*)d_in[6];
  float* out = (float*)d_out;

  char* ws = (char*)d_ws;
  const size_t hbf = (size_t)NV * BDIM * 2;       // 6.4 MB
  const size_t hTb = (size_t)NVP * BDIM * 2;      // 6.42 MB
  const size_t xpkb = (size_t)8 * XPK_N * 16;     // 2 MB
  unsigned short* hb0 = (unsigned short*)ws;
  unsigned short* hb1 = (unsigned short*)(ws + hbf);
  unsigned short* hT  = (unsigned short*)(ws + 2 * hbf);
  uint4* xpk8 = (uint4*)(ws + 2 * hbf + hTb);
  float* part = (float*)(ws + 2 * hbf + hTb + xpkb);  // 25.7 MB

  pack_x<<<32, 256, 0, stream>>>(x, xpk8);
  layer0_mfma<<<(NV + 63) / 64, 256, 0, stream>>>(W0, b0, xpk8, hb0);

  const size_t lstride = (size_t)NV * KFAN;
  sparse_layer<<<NV / 4, 256, 0, stream>>>(hb0, Wv, src, hb1);
  sparse_layer<<<NV / 4, 256, 0, stream>>>(hb1, Wv + lstride, src + lstride, hb0);
  sparse_layer<<<NV / 4, 256, 0, stream>>>(hb0, Wv + 2 * lstride, src + 2 * lstride, hb1);

  transpose_h<<<NVP / 32, 256, 0, stream>>>(hb1, hT);
  out_partial_mfma<<<dim3(4, OPC_NCH), 64, 0, stream>>>(hT, Wout, part);
  out_reduce<<<(BDIM * DOUT) / 256, 256, 0, stream>>>(part, bout, out);
}

// Round 11
// 200.727 us; speedup vs baseline: 1.0239x; 1.0108x over previous
//
#include <hip/hip_runtime.h>

#define NV 50000
#define NVP 50176
#define BDIM 64
#define DIN 1024
#define KFAN 32
#define DOUT 256
#define KSTEPS (DIN / 32)
#define XPK_N (KSTEPS * 512)   // uint4 elements per xpk copy (256 KB)
#define OPC_CHUNK 128
#define OPC_NCH (NVP / OPC_CHUNK)  // 392

typedef short bf16x8 __attribute__((ext_vector_type(8)));
typedef float f32x4 __attribute__((ext_vector_type(4)));

__device__ __forceinline__ unsigned short bf16_rtn(float f) {
  unsigned u = __float_as_uint(f);
  return (unsigned short)((u + 0x7fffu + ((u >> 16) & 1u)) >> 16);
}
__device__ __forceinline__ float bf16_to_f(unsigned short v) {
  return __uint_as_float(((unsigned)v) << 16);
}

// Pack x[64][1024] into MFMA B-fragment lane order (hi/lo bf16 split),
// replicated 8x so each XCD's L2 can hold a private copy.
__global__ __launch_bounds__(256) void pack_x(const float* __restrict__ x,
                                              uint4* __restrict__ xpk8) {
  int tid = blockIdx.x * 256 + threadIdx.x;  // 0..8191
  int ks = tid >> 8;
  int g = (tid >> 6) & 3;
  int l = tid & 63;
  int b = g * 16 + (l & 15);
  int k0 = ks * 32 + (l >> 4) * 8;
  unsigned hi[8], lo[8];
#pragma unroll
  for (int j = 0; j < 8; ++j) {
    float f = x[b * DIN + k0 + j];
    unsigned u = __float_as_uint(f);
    hi[j] = u >> 16;  // truncate to bf16
    float fh = __uint_as_float(u & 0xffff0000u);
    lo[j] = bf16_rtn(f - fh);
  }
  uint4 vh, vl;
  vh.x = hi[0] | (hi[1] << 16); vh.y = hi[2] | (hi[3] << 16);
  vh.z = hi[4] | (hi[5] << 16); vh.w = hi[6] | (hi[7] << 16);
  vl.x = lo[0] | (lo[1] << 16); vl.y = lo[2] | (lo[3] << 16);
  vl.z = lo[4] | (lo[5] << 16); vl.w = lo[6] | (lo[7] << 16);
  int idx = (ks * 4 + g) * 128 + l;
#pragma unroll
  for (int c = 0; c < 8; ++c) {
    xpk8[(size_t)c * XPK_N + idx] = vh;
    xpk8[(size_t)c * XPK_N + idx + 64] = vl;
  }
}

// h[n][b] = relu(sum_d W0[n][d]*x[b][d] + b0[n]) via split-bf16 MFMA.
// MAX-TLP variant: one wave per 16 rows, full K, no LDS, no barriers.
// 3125 independent 64-thread blocks (~12 resident waves/CU): W latency is
// hidden by cross-wave TLP (36 KB outstanding/CU >> 9 KB BDP), not by
// intra-wave pipelining. x from the XCD-local L2 copy.
__global__ __launch_bounds__(64) void layer0_mfma(
    const float* __restrict__ W0, const float* __restrict__ b0,
    const uint4* __restrict__ xpk8, unsigned short* __restrict__ h)
{
  const int lane = threadIdx.x;
  const int n_base = blockIdx.x * 16;  // NV = 3125*16 exactly
  const int rq = lane >> 4;
  const int rr = lane & 15;
  const float* wp = W0 + (size_t)(n_base + rr) * DIN + rq * 8;
  const uint4* xsrc = xpk8 + (size_t)(blockIdx.x & 7) * XPK_N;

  f32x4 acc[4];
#pragma unroll
  for (int g = 0; g < 4; ++g) acc[g] = (f32x4){0.f, 0.f, 0.f, 0.f};

  for (int ks = 0; ks < KSTEPS; ++ks) {
    // W fragment: 2 dependent 16B loads (cold HBM, hidden by TLP)
    float4 wv0 = *(const float4*)(wp + ks * 32);
    float4 wv1 = *(const float4*)(wp + ks * 32 + 4);
    // x fragments: 8 loads from L2-resident XCD-local copy
    const int xb = ks * 512;
    uint4 xc[4][2];
#pragma unroll
    for (int g = 0; g < 4; ++g) {
      xc[g][0] = xsrc[xb + g * 128 + lane];
      xc[g][1] = xsrc[xb + g * 128 + 64 + lane];
    }
    bf16x8 whi, wlo;
    {
      float wf[8] = {wv0.x, wv0.y, wv0.z, wv0.w, wv1.x, wv1.y, wv1.z, wv1.w};
#pragma unroll
      for (int e = 0; e < 8; ++e) {
        unsigned u = __float_as_uint(wf[e]);
        whi[e] = (short)(u >> 16);
        float l = wf[e] - __uint_as_float(u & 0xffff0000u);
        wlo[e] = (short)bf16_rtn(l);
      }
    }
#pragma unroll
    for (int g = 0; g < 4; ++g) {
      bf16x8 xh = __builtin_bit_cast(bf16x8, xc[g][0]);
      bf16x8 xl = __builtin_bit_cast(bf16x8, xc[g][1]);
      acc[g] = __builtin_amdgcn_mfma_f32_16x16x32_bf16(whi, xh, acc[g], 0, 0, 0);
      acc[g] = __builtin_amdgcn_mfma_f32_16x16x32_bf16(wlo, xh, acc[g], 0, 0, 0);
      acc[g] = __builtin_amdgcn_mfma_f32_16x16x32_bf16(whi, xl, acc[g], 0, 0, 0);
    }
  }

  // C layout: col = rr (b sub), row = rq*4 + r (n sub)
#pragma unroll
  for (int r = 0; r < 4; ++r) {
    int n = n_base + rq * 4 + r;
    float bias = b0[n];
#pragma unroll
    for (int g = 0; g < 4; ++g) {
      float v = fmaxf(acc[g][r] + bias, 0.f);
      h[(size_t)n * BDIM + g * 16 + rr] = bf16_rtn(v);
    }
  }
}

// h_new[n][b] = relu(sum_k wv[n][k] * h[src[n][k]][b]); one wave per n.
__global__ __launch_bounds__(256) void sparse_layer(
    const unsigned short* __restrict__ hin, const float* __restrict__ wv,
    const int* __restrict__ src, unsigned short* __restrict__ hout)
{
  const int lane = threadIdx.x & 63;
  int n = blockIdx.x * 4 + (threadIdx.x >> 6);
  n = __builtin_amdgcn_readfirstlane(n);
  const float* wrow = wv + (size_t)n * KFAN;
  const int* srow = src + (size_t)n * KFAN;
  float acc = 0.f;
#pragma unroll
  for (int k = 0; k < KFAN; ++k) {
    int s = srow[k];      // uniform scalar load
    float w = wrow[k];    // uniform scalar load
    acc = fmaf(w, bf16_to_f(hin[(size_t)s * BDIM + lane]), acc);
  }
  hout[(size_t)n * BDIM + lane] = bf16_rtn(fmaxf(acc, 0.f));
}

// hT[b][n] = h[n][b]; coalesced reads, 16B/lane stores; zero-fills n-pad.
__global__ __launch_bounds__(256) void transpose_h(
    const unsigned short* __restrict__ h, unsigned short* __restrict__ hT)
{
  const int lane = threadIdx.x & 63;              // b
  const int wv = threadIdx.x >> 6;                // wave in block
  const int n0 = (blockIdx.x * 4 + wv) * 8;       // 8 n per wave
  unsigned short v[8];
#pragma unroll
  for (int i = 0; i < 8; ++i) {
    int n = n0 + i;
    v[i] = (n < NV) ? h[(size_t)n * BDIM + lane] : (unsigned short)0;
  }
  uint4 o;
  o.x = v[0] | ((unsigned)v[1] << 16);
  o.y = v[2] | ((unsigned)v[3] << 16);
  o.z = v[4] | ((unsigned)v[5] << 16);
  o.w = v[6] | ((unsigned)v[7] << 16);
  *(uint4*)(hT + (size_t)lane * NVP + n0) = o;
}

// part[dtile][chunk][d_local][b] over 128-n chunks, split-bf16 MFMA.
__global__ __launch_bounds__(64) void out_partial_mfma(
    const unsigned short* __restrict__ hT, const float* __restrict__ Wout,
    float* __restrict__ part)
{
  const int lane = threadIdx.x;
  const int rq = lane >> 4;
  const int rr = lane & 15;
  const int dtile = blockIdx.x;   // 0..3
  const int chunk = blockIdx.y;   // 0..391

  f32x4 acc[4][4];
#pragma unroll
  for (int f = 0; f < 4; ++f)
#pragma unroll
    for (int g = 0; g < 4; ++g) acc[f][g] = (f32x4){0.f, 0.f, 0.f, 0.f};

#pragma unroll
  for (int ks = 0; ks < OPC_CHUNK / 32; ++ks) {
    const int n0 = chunk * OPC_CHUNK + ks * 32 + rq * 8;
    bf16x8 hb[4];
#pragma unroll
    for (int g = 0; g < 4; ++g)
      hb[g] = *(const bf16x8*)(hT + (size_t)(g * 16 + rr) * NVP + n0);
    int nb = n0 > (NV - 8) ? (NV - 8) : n0;  // pad region: hb==0 -> contributes 0
#pragma unroll
    for (int f = 0; f < 4; ++f) {
      const float* wp = Wout + (size_t)(dtile * 64 + f * 16 + rr) * NV + nb;
      float4 a0 = *(const float4*)(wp);
      float4 a1 = *(const float4*)(wp + 4);
      float wf[8] = {a0.x, a0.y, a0.z, a0.w, a1.x, a1.y, a1.z, a1.w};
      bf16x8 whi, wlo;
#pragma unroll
      for (int e = 0; e < 8; ++e) {
        unsigned u = __float_as_uint(wf[e]);
        whi[e] = (short)(u >> 16);
        float l = wf[e] - __uint_as_float(u & 0xffff0000u);
        wlo[e] = (short)bf16_rtn(l);
      }
#pragma unroll
      for (int g = 0; g < 4; ++g) {
        acc[f][g] = __builtin_amdgcn_mfma_f32_16x16x32_bf16(whi, hb[g], acc[f][g], 0, 0, 0);
        acc[f][g] = __builtin_amdgcn_mfma_f32_16x16x32_bf16(wlo, hb[g], acc[f][g], 0, 0, 0);
      }
    }
  }
  float* pbase = part + ((size_t)dtile * OPC_NCH + chunk) * 4096;
#pragma unroll
  for (int f = 0; f < 4; ++f)
#pragma unroll
    for (int g = 0; g < 4; ++g)
#pragma unroll
      for (int r = 0; r < 4; ++r)
        pbase[(f * 16 + rq * 4 + r) * 64 + g * 16 + rr] = acc[f][g][r];
}

__global__ __launch_bounds__(256) void out_reduce(
    const float* __restrict__ part, const float* __restrict__ bout,
    float* __restrict__ out)
{
  int tid = blockIdx.x * 256 + threadIdx.x;  // 16384 threads
  int b = tid & 63;
  int d = tid >> 6;
  int dtile = d >> 6;
  int dd = d & 63;
  float s = bout[d];
  for (int c = 0; c < OPC_NCH; ++c)
    s += part[((size_t)dtile * OPC_NCH + c) * 4096 + dd * 64 + b];
  out[(size_t)b * DOUT + d] = s;
}

extern "C" void kernel_launch(void* const* d_in, const int* in_sizes, int n_in,
                              void* d_out, int out_size, void* d_ws, size_t ws_size,
                              hipStream_t stream)
{
  const float* x    = (const float*)d_in[0];
  const float* W0   = (const float*)d_in[1];
  const float* b0   = (const float*)d_in[2];
  const float* Wv   = (const float*)d_in[3];
  const float* Wout = (const float*)d_in[4];
  const float* bout = (const float*)d_in[5];
  const int*   src  = (const int*)d_in[6];
  float* out = (float*)d_out;

  char* ws = (char*)d_ws;
  const size_t hbf = (size_t)NV * BDIM * 2;       // 6.4 MB
  const size_t hTb = (size_t)NVP * BDIM * 2;      // 6.42 MB
  const size_t xpkb = (size_t)8 * XPK_N * 16;     // 2 MB
  unsigned short* hb0 = (unsigned short*)ws;
  unsigned short* hb1 = (unsigned short*)(ws + hbf);
  unsigned short* hT  = (unsigned short*)(ws + 2 * hbf);
  uint4* xpk8 = (uint4*)(ws + 2 * hbf + hTb);
  float* part = (float*)(ws + 2 * hbf + hTb + xpkb);  // 25.7 MB

  pack_x<<<32, 256, 0, stream>>>(x, xpk8);
  layer0_mfma<<<NV / 16, 64, 0, stream>>>(W0, b0, xpk8, hb0);

  const size_t lstride = (size_t)NV * KFAN;
  sparse_layer<<<NV / 4, 256, 0, stream>>>(hb0, Wv, src, hb1);
  sparse_layer<<<NV / 4, 256, 0, stream>>>(hb1, Wv + lstride, src + lstride, hb0);
  sparse_layer<<<NV / 4, 256, 0, stream>>>(hb0, Wv + 2 * lstride, src + 2 * lstride, hb1);

  transpose_h<<<NVP / 32, 256, 0, stream>>>(hb1, hT);
  out_partial_mfma<<<dim3(4, OPC_NCH), 64, 0, stream>>>(hT, Wout, part);
  out_reduce<<<(BDIM * DOUT) / 256, 256, 0, stream>>>(part, bout, out);
}

// Round 12
// 199.183 us; speedup vs baseline: 1.0318x; 1.0077x over previous
//
#include <hip/hip_runtime.h>

#define NV 50000
#define NVP 50176
#define BDIM 64
#define DIN 1024
#define KFAN 32
#define DOUT 256
#define KSTEPS (DIN / 32)
#define XPK_N (KSTEPS * 512)   // uint4 elements per xpk copy (256 KB)
#define OPC_CHUNK 128
#define OPC_NCH (NVP / OPC_CHUNK)  // 392

typedef short bf16x8 __attribute__((ext_vector_type(8)));
typedef float f32x4 __attribute__((ext_vector_type(4)));

__device__ __forceinline__ unsigned short bf16_rtn(float f) {
  unsigned u = __float_as_uint(f);
  return (unsigned short)((u + 0x7fffu + ((u >> 16) & 1u)) >> 16);
}
__device__ __forceinline__ float bf16_to_f(unsigned short v) {
  return __uint_as_float(((unsigned)v) << 16);
}

// Pack x[64][1024] into MFMA B-fragment lane order (hi/lo bf16 split),
// replicated 8x so each XCD's L2 can hold a private copy.
__global__ __launch_bounds__(256) void pack_x(const float* __restrict__ x,
                                              uint4* __restrict__ xpk8) {
  int tid = blockIdx.x * 256 + threadIdx.x;  // 0..8191
  int ks = tid >> 8;
  int g = (tid >> 6) & 3;
  int l = tid & 63;
  int b = g * 16 + (l & 15);
  int k0 = ks * 32 + (l >> 4) * 8;
  unsigned hi[8], lo[8];
#pragma unroll
  for (int j = 0; j < 8; ++j) {
    float f = x[b * DIN + k0 + j];
    unsigned u = __float_as_uint(f);
    hi[j] = u >> 16;  // truncate to bf16
    float fh = __uint_as_float(u & 0xffff0000u);
    lo[j] = bf16_rtn(f - fh);
  }
  uint4 vh, vl;
  vh.x = hi[0] | (hi[1] << 16); vh.y = hi[2] | (hi[3] << 16);
  vh.z = hi[4] | (hi[5] << 16); vh.w = hi[6] | (hi[7] << 16);
  vl.x = lo[0] | (lo[1] << 16); vl.y = lo[2] | (lo[3] << 16);
  vl.z = lo[4] | (lo[5] << 16); vl.w = lo[6] | (lo[7] << 16);
  int idx = (ks * 4 + g) * 128 + l;
#pragma unroll
  for (int c = 0; c < 8; ++c) {
    xpk8[(size_t)c * XPK_N + idx] = vh;
    xpk8[(size_t)c * XPK_N + idx + 64] = vl;
  }
}

// h[n][b] = relu(sum_d W0[n][d]*x[b][d] + b0[n]) via split-bf16 MFMA.
// Modulo-scheduled register pipeline: W prefetched 4 ksteps deep, x 2 deep,
// k-loop FULLY unrolled (all prefetch-slot indices static). No LDS, no
// barriers, no vmcnt-drain anywhere: loads stay outstanding continuously.
__global__ __launch_bounds__(64) void layer0_mfma(
    const float* __restrict__ W0, const float* __restrict__ b0,
    const uint4* __restrict__ xpk8, unsigned short* __restrict__ h)
{
  const int lane = threadIdx.x;
  const int n_base = blockIdx.x * 16;  // NV = 3125*16 exactly
  const int rq = lane >> 4;
  const int rr = lane & 15;
  const float* wp = W0 + (size_t)(n_base + rr) * DIN + rq * 8;
  const uint4* xsrc = xpk8 + (size_t)(blockIdx.x & 7) * XPK_N;

  f32x4 acc[4];
#pragma unroll
  for (int g = 0; g < 4; ++g) acc[g] = (f32x4){0.f, 0.f, 0.f, 0.f};

  float4 wpre[4][2];   // 4-deep W pipeline (1000+ cyc slack per slot)
  uint4 xpre[2][8];    // 2-deep x pipeline (L2-resident source)

#pragma unroll
  for (int d = 0; d < 4; ++d) {
    wpre[d][0] = *(const float4*)(wp + d * 32);
    wpre[d][1] = *(const float4*)(wp + d * 32 + 4);
  }
#pragma unroll
  for (int d = 0; d < 2; ++d)
#pragma unroll
    for (int g = 0; g < 4; ++g) {
      xpre[d][g * 2]     = xsrc[d * 512 + g * 128 + lane];
      xpre[d][g * 2 + 1] = xsrc[d * 512 + g * 128 + 64 + lane];
    }

#pragma unroll
  for (int ks = 0; ks < KSTEPS; ++ks) {
    const int sw = ks & 3;
    const int sx = ks & 1;
    // take W out of its slot, then immediately refill the slot for ks+4:
    // the anti-dependency pins the issue point 4 iterations ahead of use.
    float4 wv0 = wpre[sw][0];
    float4 wv1 = wpre[sw][1];
    if (ks + 4 < KSTEPS) {
      wpre[sw][0] = *(const float4*)(wp + (ks + 4) * 32);
      wpre[sw][1] = *(const float4*)(wp + (ks + 4) * 32 + 4);
    }
    bf16x8 whi, wlo;
    {
      float wf[8] = {wv0.x, wv0.y, wv0.z, wv0.w, wv1.x, wv1.y, wv1.z, wv1.w};
#pragma unroll
      for (int e = 0; e < 8; ++e) {
        unsigned u = __float_as_uint(wf[e]);
        whi[e] = (short)(u >> 16);
        float l = wf[e] - __uint_as_float(u & 0xffff0000u);
        wlo[e] = (short)bf16_rtn(l);
      }
    }
#pragma unroll
    for (int g = 0; g < 4; ++g) {
      bf16x8 xh = __builtin_bit_cast(bf16x8, xpre[sx][g * 2]);
      bf16x8 xl = __builtin_bit_cast(bf16x8, xpre[sx][g * 2 + 1]);
      acc[g] = __builtin_amdgcn_mfma_f32_16x16x32_bf16(whi, xh, acc[g], 0, 0, 0);
      acc[g] = __builtin_amdgcn_mfma_f32_16x16x32_bf16(wlo, xh, acc[g], 0, 0, 0);
      acc[g] = __builtin_amdgcn_mfma_f32_16x16x32_bf16(whi, xl, acc[g], 0, 0, 0);
    }
    // refill x slot for ks+2 (consumed above; 2 iterations of slack)
    if (ks + 2 < KSTEPS) {
      const int xb = (ks + 2) * 512;
#pragma unroll
      for (int g = 0; g < 4; ++g) {
        xpre[sx][g * 2]     = xsrc[xb + g * 128 + lane];
        xpre[sx][g * 2 + 1] = xsrc[xb + g * 128 + 64 + lane];
      }
    }
  }

  // C layout: col = rr (b sub), row = rq*4 + r (n sub)
#pragma unroll
  for (int r = 0; r < 4; ++r) {
    int n = n_base + rq * 4 + r;
    float bias = b0[n];
#pragma unroll
    for (int g = 0; g < 4; ++g) {
      float v = fmaxf(acc[g][r] + bias, 0.f);
      h[(size_t)n * BDIM + g * 16 + rr] = bf16_rtn(v);
    }
  }
}

// h_new[n][b] = relu(sum_k wv[n][k] * h[src[n][k]][b]); one wave per n.
__global__ __launch_bounds__(256) void sparse_layer(
    const unsigned short* __restrict__ hin, const float* __restrict__ wv,
    const int* __restrict__ src, unsigned short* __restrict__ hout)
{
  const int lane = threadIdx.x & 63;
  int n = blockIdx.x * 4 + (threadIdx.x >> 6);
  n = __builtin_amdgcn_readfirstlane(n);
  const float* wrow = wv + (size_t)n * KFAN;
  const int* srow = src + (size_t)n * KFAN;
  float acc = 0.f;
#pragma unroll
  for (int k = 0; k < KFAN; ++k) {
    int s = srow[k];      // uniform scalar load
    float w = wrow[k];    // uniform scalar load
    acc = fmaf(w, bf16_to_f(hin[(size_t)s * BDIM + lane]), acc);
  }
  hout[(size_t)n * BDIM + lane] = bf16_rtn(fmaxf(acc, 0.f));
}

// hT[b][n] = h[n][b]; coalesced reads, 16B/lane stores; zero-fills n-pad.
__global__ __launch_bounds__(256) void transpose_h(
    const unsigned short* __restrict__ h, unsigned short* __restrict__ hT)
{
  const int lane = threadIdx.x & 63;              // b
  const int wv = threadIdx.x >> 6;                // wave in block
  const int n0 = (blockIdx.x * 4 + wv) * 8;       // 8 n per wave
  unsigned short v[8];
#pragma unroll
  for (int i = 0; i < 8; ++i) {
    int n = n0 + i;
    v[i] = (n < NV) ? h[(size_t)n * BDIM + lane] : (unsigned short)0;
  }
  uint4 o;
  o.x = v[0] | ((unsigned)v[1] << 16);
  o.y = v[2] | ((unsigned)v[3] << 16);
  o.z = v[4] | ((unsigned)v[5] << 16);
  o.w = v[6] | ((unsigned)v[7] << 16);
  *(uint4*)(hT + (size_t)lane * NVP + n0) = o;
}

// part[dtile][chunk][d_local][b] over 128-n chunks, split-bf16 MFMA.
__global__ __launch_bounds__(64) void out_partial_mfma(
    const unsigned short* __restrict__ hT, const float* __restrict__ Wout,
    float* __restrict__ part)
{
  const int lane = threadIdx.x;
  const int rq = lane >> 4;
  const int rr = lane & 15;
  const int dtile = blockIdx.x;   // 0..3
  const int chunk = blockIdx.y;   // 0..391

  f32x4 acc[4][4];
#pragma unroll
  for (int f = 0; f < 4; ++f)
#pragma unroll
    for (int g = 0; g < 4; ++g) acc[f][g] = (f32x4){0.f, 0.f, 0.f, 0.f};

#pragma unroll
  for (int ks = 0; ks < OPC_CHUNK / 32; ++ks) {
    const int n0 = chunk * OPC_CHUNK + ks * 32 + rq * 8;
    bf16x8 hb[4];
#pragma unroll
    for (int g = 0; g < 4; ++g)
      hb[g] = *(const bf16x8*)(hT + (size_t)(g * 16 + rr) * NVP + n0);
    int nb = n0 > (NV - 8) ? (NV - 8) : n0;  // pad region: hb==0 -> contributes 0
#pragma unroll
    for (int f = 0; f < 4; ++f) {
      const float* wp = Wout + (size_t)(dtile * 64 + f * 16 + rr) * NV + nb;
      float4 a0 = *(const float4*)(wp);
      float4 a1 = *(const float4*)(wp + 4);
      float wf[8] = {a0.x, a0.y, a0.z, a0.w, a1.x, a1.y, a1.z, a1.w};
      bf16x8 whi, wlo;
#pragma unroll
      for (int e = 0; e < 8; ++e) {
        unsigned u = __float_as_uint(wf[e]);
        whi[e] = (short)(u >> 16);
        float l = wf[e] - __uint_as_float(u & 0xffff0000u);
        wlo[e] = (short)bf16_rtn(l);
      }
#pragma unroll
      for (int g = 0; g < 4; ++g) {
        acc[f][g] = __builtin_amdgcn_mfma_f32_16x16x32_bf16(whi, hb[g], acc[f][g], 0, 0, 0);
        acc[f][g] = __builtin_amdgcn_mfma_f32_16x16x32_bf16(wlo, hb[g], acc[f][g], 0, 0, 0);
      }
    }
  }
  float* pbase = part + ((size_t)dtile * OPC_NCH + chunk) * 4096;
#pragma unroll
  for (int f = 0; f < 4; ++f)
#pragma unroll
    for (int g = 0; g < 4; ++g)
#pragma unroll
      for (int r = 0; r < 4; ++r)
        pbase[(f * 16 + rq * 4 + r) * 64 + g * 16 + rr] = acc[f][g][r];
}

__global__ __launch_bounds__(256) void out_reduce(
    const float* __restrict__ part, const float* __restrict__ bout,
    float* __restrict__ out)
{
  int tid = blockIdx.x * 256 + threadIdx.x;  // 16384 threads
  int b = tid & 63;
  int d = tid >> 6;
  int dtile = d >> 6;
  int dd = d & 63;
  float s = bout[d];
  for (int c = 0; c < OPC_NCH; ++c)
    s += part[((size_t)dtile * OPC_NCH + c) * 4096 + dd * 64 + b];
  out[(size_t)b * DOUT + d] = s;
}

extern "C" void kernel_launch(void* const* d_in, const int* in_sizes, int n_in,
                              void* d_out, int out_size, void* d_ws, size_t ws_size,
                              hipStream_t stream)
{
  const float* x    = (const float*)d_in[0];
  const float* W0   = (const float*)d_in[1];
  const float* b0   = (const float*)d_in[2];
  const float* Wv   = (const float*)d_in[3];
  const float* Wout = (const float*)d_in[4];
  const float* bout = (const float*)d_in[5];
  const int*   src  = (const int*)d_in[6];
  float* out = (float*)d_out;

  char* ws = (char*)d_ws;
  const size_t hbf = (size_t)NV * BDIM * 2;       // 6.4 MB
  const size_t hTb = (size_t)NVP * BDIM * 2;      // 6.42 MB
  const size_t xpkb = (size_t)8 * XPK_N * 16;     // 2 MB
  unsigned short* hb0 = (unsigned short*)ws;
  unsigned short* hb1 = (unsigned short*)(ws + hbf);
  unsigned short* hT  = (unsigned short*)(ws + 2 * hbf);
  uint4* xpk8 = (uint4*)(ws + 2 * hbf + hTb);
  float* part = (float*)(ws + 2 * hbf + hTb + xpkb);  // 25.7 MB

  pack_x<<<32, 256, 0, stream>>>(x, xpk8);
  layer0_mfma<<<NV / 16, 64, 0, stream>>>(W0, b0, xpk8, hb0);

  const size_t lstride = (size_t)NV * KFAN;
  sparse_layer<<<NV / 4, 256, 0, stream>>>(hb0, Wv, src, hb1);
  sparse_layer<<<NV / 4, 256, 0, stream>>>(hb1, Wv + lstride, src + lstride, hb0);
  sparse_layer<<<NV / 4, 256, 0, stream>>>(hb0, Wv + 2 * lstride, src + 2 * lstride, hb1);

  transpose_h<<<NVP / 32, 256, 0, stream>>>(hb1, hT);
  out_partial_mfma<<<dim3(4, OPC_NCH), 64, 0, stream>>>(hT, Wout, part);
  out_reduce<<<(BDIM * DOUT) / 256, 256, 0, stream>>>(part, bout, out);
}

// Round 13
// 196.211 us; speedup vs baseline: 1.0475x; 1.0151x over previous
//
#include <hip/hip_runtime.h>

#define NV 50000
#define NVP 50176
#define BDIM 64
#define DIN 1024
#define KFAN 32
#define DOUT 256
#define KSTEPS (DIN / 32)
#define XPK_N (KSTEPS * 512)   // uint4 elements per xpk copy (256 KB)
#define OPC_CHUNK 128
#define OPC_NCH (NVP / OPC_CHUNK)  // 392

typedef short bf16x8 __attribute__((ext_vector_type(8)));
typedef float f32x4 __attribute__((ext_vector_type(4)));

__device__ __forceinline__ unsigned short bf16_rtn(float f) {
  unsigned u = __float_as_uint(f);
  return (unsigned short)((u + 0x7fffu + ((u >> 16) & 1u)) >> 16);
}
__device__ __forceinline__ float bf16_to_f(unsigned short v) {
  return __uint_as_float(((unsigned)v) << 16);
}

// Pack x[64][1024] into MFMA B-fragment lane order (hi/lo bf16 split),
// replicated 8x so each XCD's L2 can hold a private copy.
__global__ __launch_bounds__(256) void pack_x(const float* __restrict__ x,
                                              uint4* __restrict__ xpk8) {
  int tid = blockIdx.x * 256 + threadIdx.x;  // 0..8191
  int ks = tid >> 8;
  int g = (tid >> 6) & 3;
  int l = tid & 63;
  int b = g * 16 + (l & 15);
  int k0 = ks * 32 + (l >> 4) * 8;
  unsigned hi[8], lo[8];
#pragma unroll
  for (int j = 0; j < 8; ++j) {
    float f = x[b * DIN + k0 + j];
    unsigned u = __float_as_uint(f);
    hi[j] = u >> 16;  // truncate to bf16
    float fh = __uint_as_float(u & 0xffff0000u);
    lo[j] = bf16_rtn(f - fh);
  }
  uint4 vh, vl;
  vh.x = hi[0] | (hi[1] << 16); vh.y = hi[2] | (hi[3] << 16);
  vh.z = hi[4] | (hi[5] << 16); vh.w = hi[6] | (hi[7] << 16);
  vl.x = lo[0] | (lo[1] << 16); vl.y = lo[2] | (lo[3] << 16);
  vl.z = lo[4] | (lo[5] << 16); vl.w = lo[6] | (lo[7] << 16);
  int idx = (ks * 4 + g) * 128 + l;
#pragma unroll
  for (int c = 0; c < 8; ++c) {
    xpk8[(size_t)c * XPK_N + idx] = vh;
    xpk8[(size_t)c * XPK_N + idx + 64] = vl;
  }
}

// h[n][b] = relu(sum_d W0[n][d]*x[b][d] + b0[n]) via split-bf16 MFMA.
// PER-BLOCK K-ROTATION: block i walks k in order (i+ks0)&31, so at any
// instant the chip reads 32 different 128B column stripes of W0 -> all HBM
// channels active (vs all blocks hammering one stripe = channel cap).
// Register pipeline from R12 kept: W 4 deep, x 2 deep, fully unrolled.
__global__ __launch_bounds__(64) void layer0_mfma(
    const float* __restrict__ W0, const float* __restrict__ b0,
    const uint4* __restrict__ xpk8, unsigned short* __restrict__ h)
{
  const int lane = threadIdx.x;
  const int n_base = blockIdx.x * 16;  // NV = 3125*16 exactly
  const int rq = lane >> 4;
  const int rr = lane & 15;
  const int koff = blockIdx.x & 31;    // k-rotation offset
  const float* wp = W0 + (size_t)(n_base + rr) * DIN + rq * 8;
  const uint4* xsrc = xpk8 + (size_t)(blockIdx.x & 7) * XPK_N;

  f32x4 acc[4];
#pragma unroll
  for (int g = 0; g < 4; ++g) acc[g] = (f32x4){0.f, 0.f, 0.f, 0.f};

  float4 wpre[4][2];   // 4-deep W pipeline
  uint4 xpre[2][8];    // 2-deep x pipeline

#pragma unroll
  for (int d = 0; d < 4; ++d) {
    const int kc = (koff + d) & 31;
    wpre[d][0] = *(const float4*)(wp + kc * 32);
    wpre[d][1] = *(const float4*)(wp + kc * 32 + 4);
  }
#pragma unroll
  for (int d = 0; d < 2; ++d) {
    const int kc = (koff + d) & 31;
#pragma unroll
    for (int g = 0; g < 4; ++g) {
      xpre[d][g * 2]     = xsrc[kc * 512 + g * 128 + lane];
      xpre[d][g * 2 + 1] = xsrc[kc * 512 + g * 128 + 64 + lane];
    }
  }

#pragma unroll
  for (int ks0 = 0; ks0 < KSTEPS; ++ks0) {
    const int sw = ks0 & 3;
    const int sx = ks0 & 1;
    float4 wv0 = wpre[sw][0];
    float4 wv1 = wpre[sw][1];
    if (ks0 + 4 < KSTEPS) {
      const int kf = (koff + ks0 + 4) & 31;
      wpre[sw][0] = *(const float4*)(wp + kf * 32);
      wpre[sw][1] = *(const float4*)(wp + kf * 32 + 4);
    }
    bf16x8 whi, wlo;
    {
      float wf[8] = {wv0.x, wv0.y, wv0.z, wv0.w, wv1.x, wv1.y, wv1.z, wv1.w};
#pragma unroll
      for (int e = 0; e < 8; ++e) {
        unsigned u = __float_as_uint(wf[e]);
        whi[e] = (short)(u >> 16);
        float l = wf[e] - __uint_as_float(u & 0xffff0000u);
        wlo[e] = (short)bf16_rtn(l);
      }
    }
#pragma unroll
    for (int g = 0; g < 4; ++g) {
      bf16x8 xh = __builtin_bit_cast(bf16x8, xpre[sx][g * 2]);
      bf16x8 xl = __builtin_bit_cast(bf16x8, xpre[sx][g * 2 + 1]);
      acc[g] = __builtin_amdgcn_mfma_f32_16x16x32_bf16(whi, xh, acc[g], 0, 0, 0);
      acc[g] = __builtin_amdgcn_mfma_f32_16x16x32_bf16(wlo, xh, acc[g], 0, 0, 0);
      acc[g] = __builtin_amdgcn_mfma_f32_16x16x32_bf16(whi, xl, acc[g], 0, 0, 0);
    }
    if (ks0 + 2 < KSTEPS) {
      const int kf = (koff + ks0 + 2) & 31;
      const int xb = kf * 512;
#pragma unroll
      for (int g = 0; g < 4; ++g) {
        xpre[sx][g * 2]     = xsrc[xb + g * 128 + lane];
        xpre[sx][g * 2 + 1] = xsrc[xb + g * 128 + 64 + lane];
      }
    }
  }

  // C layout: col = rr (b sub), row = rq*4 + r (n sub)
#pragma unroll
  for (int r = 0; r < 4; ++r) {
    int n = n_base + rq * 4 + r;
    float bias = b0[n];
#pragma unroll
    for (int g = 0; g < 4; ++g) {
      float v = fmaxf(acc[g][r] + bias, 0.f);
      h[(size_t)n * BDIM + g * 16 + rr] = bf16_rtn(v);
    }
  }
}

// h_new[n][b] = relu(sum_k wv[n][k] * h[src[n][k]][b]); one wave per n.
__global__ __launch_bounds__(256) void sparse_layer(
    const unsigned short* __restrict__ hin, const float* __restrict__ wv,
    const int* __restrict__ src, unsigned short* __restrict__ hout)
{
  const int lane = threadIdx.x & 63;
  int n = blockIdx.x * 4 + (threadIdx.x >> 6);
  n = __builtin_amdgcn_readfirstlane(n);
  const float* wrow = wv + (size_t)n * KFAN;
  const int* srow = src + (size_t)n * KFAN;
  float acc = 0.f;
#pragma unroll
  for (int k = 0; k < KFAN; ++k) {
    int s = srow[k];      // uniform scalar load
    float w = wrow[k];    // uniform scalar load
    acc = fmaf(w, bf16_to_f(hin[(size_t)s * BDIM + lane]), acc);
  }
  hout[(size_t)n * BDIM + lane] = bf16_rtn(fmaxf(acc, 0.f));
}

// hT[b][n] = h[n][b]; coalesced reads, 16B/lane stores; zero-fills n-pad.
__global__ __launch_bounds__(256) void transpose_h(
    const unsigned short* __restrict__ h, unsigned short* __restrict__ hT)
{
  const int lane = threadIdx.x & 63;              // b
  const int wv = threadIdx.x >> 6;                // wave in block
  const int n0 = (blockIdx.x * 4 + wv) * 8;       // 8 n per wave
  unsigned short v[8];
#pragma unroll
  for (int i = 0; i < 8; ++i) {
    int n = n0 + i;
    v[i] = (n < NV) ? h[(size_t)n * BDIM + lane] : (unsigned short)0;
  }
  uint4 o;
  o.x = v[0] | ((unsigned)v[1] << 16);
  o.y = v[2] | ((unsigned)v[3] << 16);
  o.z = v[4] | ((unsigned)v[5] << 16);
  o.w = v[6] | ((unsigned)v[7] << 16);
  *(uint4*)(hT + (size_t)lane * NVP + n0) = o;
}

// part[dtile][chunk][d_local][b] over 128-n chunks, split-bf16 MFMA.
__global__ __launch_bounds__(64) void out_partial_mfma(
    const unsigned short* __restrict__ hT, const float* __restrict__ Wout,
    float* __restrict__ part)
{
  const int lane = threadIdx.x;
  const int rq = lane >> 4;
  const int rr = lane & 15;
  const int dtile = blockIdx.x;   // 0..3
  const int chunk = blockIdx.y;   // 0..391

  f32x4 acc[4][4];
#pragma unroll
  for (int f = 0; f < 4; ++f)
#pragma unroll
    for (int g = 0; g < 4; ++g) acc[f][g] = (f32x4){0.f, 0.f, 0.f, 0.f};

#pragma unroll
  for (int ks = 0; ks < OPC_CHUNK / 32; ++ks) {
    const int n0 = chunk * OPC_CHUNK + ks * 32 + rq * 8;
    bf16x8 hb[4];
#pragma unroll
    for (int g = 0; g < 4; ++g)
      hb[g] = *(const bf16x8*)(hT + (size_t)(g * 16 + rr) * NVP + n0);
    int nb = n0 > (NV - 8) ? (NV - 8) : n0;  // pad region: hb==0 -> contributes 0
#pragma unroll
    for (int f = 0; f < 4; ++f) {
      const float* wp = Wout + (size_t)(dtile * 64 + f * 16 + rr) * NV + nb;
      float4 a0 = *(const float4*)(wp);
      float4 a1 = *(const float4*)(wp + 4);
      float wf[8] = {a0.x, a0.y, a0.z, a0.w, a1.x, a1.y, a1.z, a1.w};
      bf16x8 whi, wlo;
#pragma unroll
      for (int e = 0; e < 8; ++e) {
        unsigned u = __float_as_uint(wf[e]);
        whi[e] = (short)(u >> 16);
        float l = wf[e] - __uint_as_float(u & 0xffff0000u);
        wlo[e] = (short)bf16_rtn(l);
      }
#pragma unroll
      for (int g = 0; g < 4; ++g) {
        acc[f][g] = __builtin_amdgcn_mfma_f32_16x16x32_bf16(whi, hb[g], acc[f][g], 0, 0, 0);
        acc[f][g] = __builtin_amdgcn_mfma_f32_16x16x32_bf16(wlo, hb[g], acc[f][g], 0, 0, 0);
      }
    }
  }
  float* pbase = part + ((size_t)dtile * OPC_NCH + chunk) * 4096;
#pragma unroll
  for (int f = 0; f < 4; ++f)
#pragma unroll
    for (int g = 0; g < 4; ++g)
#pragma unroll
      for (int r = 0; r < 4; ++r)
        pbase[(f * 16 + rq * 4 + r) * 64 + g * 16 + rr] = acc[f][g][r];
}

__global__ __launch_bounds__(256) void out_reduce(
    const float* __restrict__ part, const float* __restrict__ bout,
    float* __restrict__ out)
{
  int tid = blockIdx.x * 256 + threadIdx.x;  // 16384 threads
  int b = tid & 63;
  int d = tid >> 6;
  int dtile = d >> 6;
  int dd = d & 63;
  float s = bout[d];
  for (int c = 0; c < OPC_NCH; ++c)
    s += part[((size_t)dtile * OPC_NCH + c) * 4096 + dd * 64 + b];
  out[(size_t)b * DOUT + d] = s;
}

extern "C" void kernel_launch(void* const* d_in, const int* in_sizes, int n_in,
                              void* d_out, int out_size, void* d_ws, size_t ws_size,
                              hipStream_t stream)
{
  const float* x    = (const float*)d_in[0];
  const float* W0   = (const float*)d_in[1];
  const float* b0   = (const float*)d_in[2];
  const float* Wv   = (const float*)d_in[3];
  const float* Wout = (const float*)d_in[4];
  const float* bout = (const float*)d_in[5];
  const int*   src  = (const int*)d_in[6];
  float* out = (float*)d_out;

  char* ws = (char*)d_ws;
  const size_t hbf = (size_t)NV * BDIM * 2;       // 6.4 MB
  const size_t hTb = (size_t)NVP * BDIM * 2;      // 6.42 MB
  const size_t xpkb = (size_t)8 * XPK_N * 16;     // 2 MB
  unsigned short* hb0 = (unsigned short*)ws;
  unsigned short* hb1 = (unsigned short*)(ws + hbf);
  unsigned short* hT  = (unsigned short*)(ws + 2 * hbf);
  uint4* xpk8 = (uint4*)(ws + 2 * hbf + hTb);
  float* part = (float*)(ws + 2 * hbf + hTb + xpkb);  // 25.7 MB

  pack_x<<<32, 256, 0, stream>>>(x, xpk8);
  layer0_mfma<<<NV / 16, 64, 0, stream>>>(W0, b0, xpk8, hb0);

  const size_t lstride = (size_t)NV * KFAN;
  sparse_layer<<<NV / 4, 256, 0, stream>>>(hb0, Wv, src, hb1);
  sparse_layer<<<NV / 4, 256, 0, stream>>>(hb1, Wv + lstride, src + lstride, hb0);
  sparse_layer<<<NV / 4, 256, 0, stream>>>(hb0, Wv + 2 * lstride, src + 2 * lstride, hb1);

  transpose_h<<<NVP / 32, 256, 0, stream>>>(hb1, hT);
  out_partial_mfma<<<dim3(4, OPC_NCH), 64, 0, stream>>>(hT, Wout, part);
  out_reduce<<<(BDIM * DOUT) / 256, 256, 0, stream>>>(part, bout, out);
}